// Round 1
// 713.506 us; speedup vs baseline: 1.1118x; 1.1118x over previous
//
#include <hip/hip_runtime.h>

#define N_ROWS 100000
#define DM 256
#define NS 512

typedef __attribute__((ext_vector_type(8))) short short8;
typedef __attribute__((ext_vector_type(4))) float floatx4;

__device__ __forceinline__ unsigned short f2bf(float x) {
  unsigned int u = __float_as_uint(x);
  u += 0x7fff + ((u >> 16) & 1);   // round-to-nearest-even bf16
  return (unsigned short)(u >> 16);
}
__device__ __forceinline__ float bf2f(unsigned short h) {
  return __uint_as_float(((unsigned int)h) << 16);
}

// Swizzled 16B-granule index within a [rows][32-short] tile (64 B per row =
// 4 granules). XOR of a row-derived pair into the granule slot makes
// 16-consecutive-row column reads (ds_read_b128, col16 fixed per lq group)
// a uniform 2-way bank pattern (free), instead of 8-way on a linear tile.
__device__ __forceinline__ int swz(int row, int col16) {
  return row * 4 + (col16 ^ ((row >> 1) & 3));
}

// ---------------------------------------------------------------------------
// Prep: per memory, build tiled + swizzled bf16 layouts in ws (shorts):
//   [0]       Mh : 16 tiles (tile = kc*2+sc) of [256 slots][32 cols]  (8192 shorts each)
//   [131072]  Ml : same tiling, lo-part
//   [262144]  Mt : 16 tiles (tile = kc2)     of [256 d][32 slots], hi only
// Tiles are stored in the exact linear order global_load_lds writes LDS,
// with the bank swizzle baked into the granule order.
// ---------------------------------------------------------------------------
__global__ __launch_bounds__(256) void prep_split(const float* __restrict__ mA,
                                                  const float* __restrict__ mS,
                                                  unsigned short* __restrict__ ws) {
  const int mem = blockIdx.y;
  const float* M = mem ? mS : mA;
  unsigned short* base = ws + (size_t)mem * 3 * (NS * DM);
  const int t = blockIdx.x * 256 + threadIdx.x;  // grid.x = 512 -> 131072 threads
  const float x = M[t];
  const unsigned short h = f2bf(x);
  const unsigned short l = f2bf(x - bf2f(h));
  const int slot = t >> 8;
  const int d = t & (DM - 1);
  {
    const int kc = d >> 5, c = d & 31;
    const int sc = slot >> 8, srow = slot & 255;
    const int tile = kc * 2 + sc;
    const int g = swz(srow, c >> 3);
    base[tile * 8192 + g * 8 + (c & 7)] = h;
    base[NS * DM + tile * 8192 + g * 8 + (c & 7)] = l;
  }
  {
    const int kc2 = slot >> 5, cs = slot & 31;
    const int g = swz(d, cs >> 3);
    base[2 * NS * DM + kc2 * 8192 + g * 8 + (cs & 7)] = h;
  }
}

// Async global->LDS, 16 B per lane. LDS base must be wave-uniform; HW adds
// lane*16. Source granule order in ws matches LDS order exactly.
__device__ __forceinline__ void async16(const void* g, void* l) {
  typedef const __attribute__((address_space(1))) unsigned int GU;
  typedef __attribute__((address_space(3))) unsigned int LU;
  __builtin_amdgcn_global_load_lds((GU*)g, (LU*)l, 16, 0, 0);
}

// Stage one 16 KB tile (8192 shorts): 4 rounds x 256 threads x 16 B.
__device__ __forceinline__ void dma_tile(const unsigned short* __restrict__ g,
                                         unsigned short* l, int tid) {
  unsigned short* lw = l + (tid >> 6) * 512;      // wave-uniform LDS base
  const unsigned short* gp = g + tid * 8;         // per-lane global addr
  #pragma unroll
  for (int r = 0; r < 4; ++r)
    async16(gp + r * 2048, lw + r * 2048);
}

// ---------------------------------------------------------------------------
// Main fused kernel. One block = 4 waves = 64 query rows, one memory.
// Wave w: rows (w&1)*32..+31, slot quarter wq = w>>1.
// All M/Mt staging is global_load_lds DMA, double-buffered, issued one full
// compute phase before the __syncthreads() that consumes (drains) it.
// LDS map (shorts):
//   0..16383     Mbuf0 (hi 0..8191, lo 8192..16383); phase2: mtbuf0/mtbuf1
//   16384..32767 Mbuf1
//   32768..34815 Qh   ; phase2: PS[0]
//   34816..36863 Ql   ; phase2: PS[1]
// ---------------------------------------------------------------------------
__global__ __launch_bounds__(256, 2) void attn_main(
    const float* __restrict__ q,
    const unsigned short* __restrict__ ws,
    float* __restrict__ out) {
  __shared__ __align__(16) unsigned short sm[36864];
  __shared__ float redmax[4][64];
  __shared__ float redsum[4][64];

  const int tid = threadIdx.x;
  const int w   = tid >> 6;
  const int l   = tid & 63;
  const int l15 = l & 15;
  const int lq  = l >> 4;
  const int mem = blockIdx.y;
  const int qbase = blockIdx.x * 64;
  const int wrow = (w & 1) * 32;
  const int wq   = w >> 1;

  const unsigned short* MhT = ws + (size_t)mem * 3 * (NS * DM);
  const unsigned short* MlT = MhT + NS * DM;
  const unsigned short* MtT = MhT + 2 * NS * DM;
  float* outM = out + (size_t)mem * N_ROWS * (2 * DM);

  auto issue_m = [&](int j) {   // phase-1 tile j -> Mbuf[j&1] (hi+lo, 32 KB)
    dma_tile(MhT + j * 8192, sm + (j & 1) * 16384, tid);
    dma_tile(MlT + j * 8192, sm + (j & 1) * 16384 + 8192, tid);
  };
  auto issue_mt = [&](int j) {  // phase-2 tile j -> mtbuf[j&1] (16 KB)
    dma_tile(MtT + j * 8192, sm + (j & 1) * 8192, tid);
  };

  float4 qa, qb;                 // Q prefetch regs (one kc ahead)
  auto load_q = [&](int kc) {
    int grow = qbase + (tid >> 2);
    if (grow >= N_ROWS) grow = N_ROWS - 1;   // clamp; garbage rows never stored
    const float* src = q + (size_t)grow * DM + kc * 32 + (tid & 3) * 8;
    qa = *(const float4*)src;
    qb = *(const float4*)(src + 4);
  };
  auto split_write_q = [&]() {   // split qa/qb into Qh/Ql (swizzled)
    const int row = tid >> 2, o = tid & 3;
    const float xs[8] = {qa.x, qa.y, qa.z, qa.w, qb.x, qb.y, qb.z, qb.w};
    union { short8 v; unsigned short s[8]; } uh, ul;
    #pragma unroll
    for (int e = 0; e < 8; ++e) {
      const unsigned short hh = f2bf(xs[e]);
      uh.s[e] = hh;
      ul.s[e] = f2bf(xs[e] - bf2f(hh));
    }
    const int g = swz(row, o);
    *(short8*)(sm + 32768 + g * 8) = uh.v;
    *(short8*)(sm + 34816 + g * 8) = ul.v;
  };
  auto store_qcopy = [&](int kc) {  // fused out[:,0:256] copy from Q regs
    const int grow = qbase + (tid >> 2);
    if (grow < N_ROWS) {
      float* dst = outM + (size_t)grow * (2 * DM) + kc * 32 + (tid & 3) * 8;
      *(float4*)dst = qa;
      *(float4*)(dst + 4) = qb;
    }
  };

  floatx4 acc[2][16];
  #pragma unroll
  for (int rt = 0; rt < 2; ++rt)
    #pragma unroll
    for (int j = 0; j < 16; ++j) acc[rt][j] = (floatx4){0.f, 0.f, 0.f, 0.f};

  // ---- prologue: Q(0) + tile0 in flight, then Q(0) visible, tile1 + Q(1) in flight
  load_q(0);
  issue_m(0);
  __syncthreads();               // tile0 + Q(0) regs drained
  split_write_q();
  __syncthreads();               // Qbuf(0) visible
  issue_m(1);
  store_qcopy(0);
  load_q(1);

  // ================= Phase 1: scores =================
  for (int kc = 0; kc < 8; ++kc) {
    short8 ah[2], al[2];
    #pragma unroll
    for (int rt = 0; rt < 2; ++rt) {
      const int g = swz(wrow + rt * 16 + l15, lq);
      ah[rt] = *(const short8*)(sm + 32768 + g * 8);
      al[rt] = *(const short8*)(sm + 34816 + g * 8);
    }
    // ---- sc = 0 (Mbuf0); DMA of tile 2kc+1 is in flight under this
    __builtin_amdgcn_s_setprio(1);
    #pragma unroll
    for (int nt = 0; nt < 8; ++nt) {
      const int g = swz(wq * 128 + nt * 16 + l15, lq);
      const short8 bh = *(const short8*)(sm + g * 8);
      const short8 bl = *(const short8*)(sm + 8192 + g * 8);
      #pragma unroll
      for (int rt = 0; rt < 2; ++rt) {
        floatx4 c = acc[rt][nt];
        c = __builtin_amdgcn_mfma_f32_16x16x32_bf16(ah[rt], bh, c, 0, 0, 0);
        c = __builtin_amdgcn_mfma_f32_16x16x32_bf16(ah[rt], bl, c, 0, 0, 0);
        c = __builtin_amdgcn_mfma_f32_16x16x32_bf16(al[rt], bh, c, 0, 0, 0);
        acc[rt][nt] = c;
      }
    }
    __builtin_amdgcn_s_setprio(0);
    __syncthreads();                       // B1a: tile 2kc+1 ready, Mbuf0 free
    if (kc < 7) issue_m(2 * kc + 2);       // overlaps sc=1 compute
    // ---- sc = 1 (Mbuf1)
    __builtin_amdgcn_s_setprio(1);
    #pragma unroll
    for (int nt = 0; nt < 8; ++nt) {
      const int g = swz(wq * 128 + nt * 16 + l15, lq);
      const short8 bh = *(const short8*)(sm + 16384 + g * 8);
      const short8 bl = *(const short8*)(sm + 24576 + g * 8);
      #pragma unroll
      for (int rt = 0; rt < 2; ++rt) {
        floatx4 c = acc[rt][8 + nt];
        c = __builtin_amdgcn_mfma_f32_16x16x32_bf16(ah[rt], bh, c, 0, 0, 0);
        c = __builtin_amdgcn_mfma_f32_16x16x32_bf16(ah[rt], bl, c, 0, 0, 0);
        c = __builtin_amdgcn_mfma_f32_16x16x32_bf16(al[rt], bh, c, 0, 0, 0);
        acc[rt][8 + nt] = c;
      }
    }
    __builtin_amdgcn_s_setprio(0);
    if (kc < 7) {
      __syncthreads();                     // B1b: tile 2kc+2 ready, Mbuf1+Qbuf free
      split_write_q();                     // Q(kc+1) (regs loaded one kc ago)
      __syncthreads();                     // B2: Qbuf visible (lgkm only, cheap)
      issue_m(2 * kc + 3);                 // overlaps next kc's sc=0 compute
      store_qcopy(kc + 1);
      if (kc < 6) load_q(kc + 2);
    }
  }

  // ================= Softmax (row-wise over 512 slots) =================
  float rowm[2][4], rowinv[2][4];
  {
    float pm[2][4];
    #pragma unroll
    for (int rt = 0; rt < 2; ++rt)
      #pragma unroll
      for (int r = 0; r < 4; ++r) {
        float m = -1e30f;
        #pragma unroll
        for (int j = 0; j < 16; ++j) m = fmaxf(m, acc[rt][j][r]);
        pm[rt][r] = m;
      }
    #pragma unroll
    for (int off = 1; off <= 8; off <<= 1)
      #pragma unroll
      for (int rt = 0; rt < 2; ++rt)
        #pragma unroll
        for (int r = 0; r < 4; ++r)
          pm[rt][r] = fmaxf(pm[rt][r], __shfl_xor(pm[rt][r], off));
    if (l15 == 0) {
      #pragma unroll
      for (int rt = 0; rt < 2; ++rt)
        #pragma unroll
        for (int r = 0; r < 4; ++r)
          redmax[w][wrow + rt * 16 + lq * 4 + r] = pm[rt][r];
    }
    __syncthreads();                       // S1: all waves past phase 1
    issue_mt(0);                           // Mt tiles 0,1 land under the exp loop
    issue_mt(1);
    #pragma unroll
    for (int rt = 0; rt < 2; ++rt)
      #pragma unroll
      for (int r = 0; r < 4; ++r) {
        const int row = wrow + rt * 16 + lq * 4 + r;
        rowm[rt][r] = fmaxf(redmax[w][row], redmax[w ^ 2][row]);
      }
    float psum[2][4] = {{0.f, 0.f, 0.f, 0.f}, {0.f, 0.f, 0.f, 0.f}};
    #pragma unroll
    for (int rt = 0; rt < 2; ++rt)
      #pragma unroll
      for (int j = 0; j < 16; ++j) {
        floatx4 c = acc[rt][j];
        #pragma unroll
        for (int r = 0; r < 4; ++r) {
          const float e = __expf(c[r] - rowm[rt][r]);
          c[r] = e;
          psum[rt][r] += e;
        }
        acc[rt][j] = c;
      }
    #pragma unroll
    for (int off = 1; off <= 8; off <<= 1)
      #pragma unroll
      for (int rt = 0; rt < 2; ++rt)
        #pragma unroll
        for (int r = 0; r < 4; ++r)
          psum[rt][r] += __shfl_xor(psum[rt][r], off);
    if (l15 == 0) {
      #pragma unroll
      for (int rt = 0; rt < 2; ++rt)
        #pragma unroll
        for (int r = 0; r < 4; ++r)
          redsum[w][wrow + rt * 16 + lq * 4 + r] = psum[rt][r];
    }
    __syncthreads();                       // S2: Mt 0,1 drained (hidden by exp)
    #pragma unroll
    for (int rt = 0; rt < 2; ++rt)
      #pragma unroll
      for (int r = 0; r < 4; ++r) {
        const int row = wrow + rt * 16 + lq * 4 + r;
        rowinv[rt][r] = 1.f / (redsum[w][row] + redsum[w ^ 2][row]);
      }
  }

  // ================= Phase 2: O^T = Mt @ P^T =================
  floatx4 oacc[4][4];
  #pragma unroll
  for (int mt = 0; mt < 4; ++mt)
    #pragma unroll
    for (int nt = 0; nt < 4; ++nt) oacc[mt][nt] = (floatx4){0.f, 0.f, 0.f, 0.f};

  auto write_ps = [&](int c) {   // owning wave-pair writes P chunk c -> PS[c&1]
    const int scp = c >> 3, nt0 = (c & 3) * 2;
    const int b = 32768 + (c & 1) * 2048;
    #pragma unroll
    for (int nn = 0; nn < 2; ++nn)
      #pragma unroll
      for (int rt = 0; rt < 2; ++rt) {
        const floatx4 v = acc[rt][scp * 8 + nt0 + nn];
        #pragma unroll
        for (int r = 0; r < 4; ++r) {
          const int row = wrow + rt * 16 + lq * 4 + r;
          const int col = nn * 16 + l15;
          sm[b + swz(row, col >> 3) * 8 + (col & 7)] =
              f2bf(v[r] * rowinv[rt][r]);
        }
      }
  };

  if (wq == 0) write_ps(0);
  __syncthreads();                         // P2: PS[0] visible
  #pragma unroll
  for (int kc2 = 0; kc2 < 16; ++kc2) {
    const unsigned short* mtb = sm + (kc2 & 1) * 8192;
    const unsigned short* ps  = sm + 32768 + (kc2 & 1) * 2048;
    short8 bfr[4];
    #pragma unroll
    for (int nt = 0; nt < 4; ++nt)
      bfr[nt] = *(const short8*)(ps + swz(nt * 16 + l15, lq) * 8);
    __builtin_amdgcn_s_setprio(1);
    #pragma unroll
    for (int mt = 0; mt < 4; ++mt) {
      const short8 a = *(const short8*)(mtb + swz(w * 64 + mt * 16 + l15, lq) * 8);
      #pragma unroll
      for (int nt = 0; nt < 4; ++nt)
        oacc[mt][nt] =
            __builtin_amdgcn_mfma_f32_16x16x32_bf16(a, bfr[nt], oacc[mt][nt], 0, 0, 0);
    }
    __builtin_amdgcn_s_setprio(0);
    if (kc2 < 15 && wq == (((kc2 + 1) >> 2) & 1)) write_ps(kc2 + 1);
    __syncthreads();                       // compute done; DMA kc2+1 drained; PS vis
    if (kc2 < 14) issue_mt(kc2 + 2);       // overlaps next compute
  }

  // store O^T: C-frag rows are d (contiguous per lane -> float4), cols are qrow
  #pragma unroll
  for (int mt = 0; mt < 4; ++mt)
    #pragma unroll
    for (int nt = 0; nt < 4; ++nt) {
      const int grow = qbase + nt * 16 + l15;
      if (grow < N_ROWS) {
        const int d0 = w * 64 + mt * 16 + lq * 4;
        *(floatx4*)(outM + (size_t)grow * (2 * DM) + DM + d0) = oacc[mt][nt];
      }
    }
}

extern "C" void kernel_launch(void* const* d_in, const int* in_sizes, int n_in,
                              void* d_out, int out_size, void* d_ws, size_t ws_size,
                              hipStream_t stream) {
  const float* query = (const float*)d_in[0];
  const float* mA    = (const float*)d_in[1];
  const float* mS    = (const float*)d_in[2];
  float* out = (float*)d_out;
  unsigned short* ws = (unsigned short*)d_ws;  // needs 1.5 MB

  hipLaunchKernelGGL(prep_split, dim3(512, 2), dim3(256), 0, stream, mA, mS, ws);
  hipLaunchKernelGGL(attn_main, dim3((N_ROWS + 63) / 64, 2), dim3(256), 0, stream,
                     query, ws, out);
}